// Round 2
// baseline (437.518 us; speedup 1.0000x reference)
//
#include <hip/hip_runtime.h>

typedef unsigned short u16;
typedef __attribute__((ext_vector_type(8))) short short8;
typedef __attribute__((ext_vector_type(4))) float f32x4;

#define AS1C(p) ((const __attribute__((address_space(1))) void*)(p))
#define AS3(p)  ((__attribute__((address_space(3))) void*)(p))

constexpr int CC    = 256;      // channels
constexpr int HWSZ  = 4096;     // H*W
constexpr int NNODE = 131072;   // B*H*W
constexpr int EEDG  = 524288;   // edges
constexpr int CAP   = 32;       // per-node bucket capacity (Poisson(4): P(deg>=32)~1e-18)

__device__ __forceinline__ float bf2f(u16 h){ unsigned u = ((unsigned)h)<<16; float f; __builtin_memcpy(&f,&u,4); return f; }
__device__ __forceinline__ u16 f2bf(float f){ unsigned u; __builtin_memcpy(&u,&f,4); return (u16)((u + 0x7FFFu + ((u>>16)&1u))>>16); }
__device__ __forceinline__ float gelu_exact(float v){ return 0.5f*v*(1.0f + erff(v*0.7071067811865476f)); }

// ---------------- fp32 64x64 tiled transpose + bf16 hi/lo split ----------------
// reads src[z*sb_in + (by*64+r)*Ccols + bx*64+c]  (fp32)
// writes dhi/dlo[z*sb_out + (bx*64+p)*R + by*64+c2]  (bf16), dlo optional
__global__ __launch_bounds__(256) void transpose_split(const float* __restrict__ src,
                                                       u16* __restrict__ dhi, u16* __restrict__ dlo,
                                                       int R, int Ccols, size_t sb_in, size_t sb_out)
{
  __shared__ float t[64][65];
  const float* s = src + blockIdx.z*sb_in + (size_t)(blockIdx.y*64)*Ccols + blockIdx.x*64;
  size_t obase   = blockIdx.z*sb_out + (size_t)(blockIdx.x*64)*R + blockIdx.y*64;
  int tid = threadIdx.x;
  for (int i=0;i<4;++i){
    int idx = i*256 + tid;           // 1024 float4 loads
    int r = idx>>4, q = idx&15;
    float4 v = *(const float4*)(s + (size_t)r*Ccols + q*4);
    t[r][q*4+0]=v.x; t[r][q*4+1]=v.y; t[r][q*4+2]=v.z; t[r][q*4+3]=v.w;
  }
  __syncthreads();
  for (int i=0;i<2;++i){
    int idx = i*256 + tid;           // 512 8-wide bf16 outputs
    int rr = idx>>3, ch = idx&7;
    u16 hi[8], lo[8];
    for (int j=0;j<8;++j){
      float f = t[ch*8+j][rr];
      u16 h = f2bf(f); hi[j] = h;
      lo[j] = f2bf(f - bf2f(h));
    }
    *(uint4*)(dhi + obase + (size_t)rr*R + ch*8) = *(uint4*)hi;
    if (dlo) *(uint4*)(dlo + obase + (size_t)rr*R + ch*8) = *(uint4*)lo;
  }
}

// ---------------- split-precision GEMM: C[m,n] = sum_k A[m,k]*B[k,n] + bias[n] ----------------
// A given as Ahi(+Alo) [M,256] bf16; B given as Bthi(+Btlo) [256,256] bf16 row-major transposed
// (Bt[n,k] = B[k,n]). acc = Ahi*Bhi + Alo*Bhi + Ahi*Blo  (~fp32 accuracy).
// Output: Chi bf16 (+Clo bf16 residual, optional). BM=BN=128, BK=32, 4 waves of 64x64.
__global__ __launch_bounds__(256) void gemm_split(const u16* __restrict__ Ahi, const u16* __restrict__ Alo,
                                                  const u16* __restrict__ Bhi, const u16* __restrict__ Blo,
                                                  const float* __restrict__ bias,
                                                  u16* __restrict__ Chi, u16* __restrict__ Clo)
{
  __shared__ u16 As_hi[128*32];
  __shared__ u16 As_lo[128*32];
  __shared__ u16 Bs_hi[128*32];
  __shared__ u16 Bs_lo[128*32];
  const int tid  = threadIdx.x;
  const int wid  = tid>>6, lane = tid&63;
  const int row0 = blockIdx.x*128;
  const int col0 = blockIdx.y*128;
  const int gk = lane>>4, ml = lane&15;
  const int wm = wid>>1, wn = wid&1;
  const bool haslo = (Alo != nullptr);

  f32x4 acc[4][4];
  for (int i=0;i<4;++i) for (int j=0;j<4;++j) for (int e=0;e<4;++e) acc[i][j][e]=0.f;

  for (int kt=0; kt<256; kt+=32) {
#define STAGE(G, S, rbase)                                                            \
    for (int it=0; it<2; ++it) {                                                      \
      int qb = (it*4+wid)*64;                                                         \
      int qq = qb + lane;                                                             \
      int m  = qq>>2, sc = qq&3;                                                      \
      int gs = sc ^ ((m>>1)&3);                                                       \
      __builtin_amdgcn_global_load_lds(AS1C(G + (size_t)((rbase)+m)*256 + kt + gs*8), \
                                       AS3(S + (size_t)qb*8), 16, 0, 0);              \
    }
    STAGE(Ahi, As_hi, row0)
    if (haslo) { STAGE(Alo, As_lo, row0) }
    STAGE(Bhi, Bs_hi, col0)
    STAGE(Blo, Bs_lo, col0)
#undef STAGE
    asm volatile("s_waitcnt vmcnt(0)" ::: "memory");
    __syncthreads();

    short8 ah[4], al[4], bh[4], bl[4];
    for (int f=0; f<4; ++f) {
      int m  = wm*64 + f*16 + ml;
      int sa = gk ^ ((m>>1)&3);
      ah[f] = *(const short8*)&As_hi[m*32 + sa*8];
      if (haslo) al[f] = *(const short8*)&As_lo[m*32 + sa*8];
      int j  = wn*64 + f*16 + ml;
      int sb = gk ^ ((j>>1)&3);
      bh[f] = *(const short8*)&Bs_hi[j*32 + sb*8];
      bl[f] = *(const short8*)&Bs_lo[j*32 + sb*8];
    }
    for (int fm=0; fm<4; ++fm)
      for (int fn=0; fn<4; ++fn) {
        acc[fm][fn] = __builtin_amdgcn_mfma_f32_16x16x32_bf16(ah[fm], bh[fn], acc[fm][fn], 0, 0, 0);
        if (haslo)
          acc[fm][fn] = __builtin_amdgcn_mfma_f32_16x16x32_bf16(al[fm], bh[fn], acc[fm][fn], 0, 0, 0);
        acc[fm][fn] = __builtin_amdgcn_mfma_f32_16x16x32_bf16(ah[fm], bl[fn], acc[fm][fn], 0, 0, 0);
      }
    __syncthreads();
  }

  float bv[4];
  for (int f=0; f<4; ++f) bv[f] = bias ? bias[col0 + wn*64 + f*16 + ml] : 0.f;
  for (int fm=0; fm<4; ++fm) {
    int rbase = row0 + wm*64 + fm*16 + gk*4;
    for (int fn=0; fn<4; ++fn) {
      int ccol = col0 + wn*64 + fn*16 + ml;
      for (int i=0;i<4;++i) {
        float f = acc[fm][fn][i] + bv[fn];
        size_t idx = (size_t)(rbase+i)*256 + ccol;
        u16 h = f2bf(f);
        Chi[idx] = h;
        if (Clo) Clo[idx] = f2bf(f - bf2f(h));
      }
    }
  }
}

// ---------------- graph prep (int32 edges) ----------------
__global__ void count_deg(const int* __restrict__ col, int* __restrict__ cnt){
  int e = blockIdx.x*256 + threadIdx.x;
  if (e < EEDG) atomicAdd(&cnt[col[e]], 1);
}
__global__ void calc_dinv(const int* __restrict__ cnt, float* __restrict__ dinv){
  int n = blockIdx.x*256 + threadIdx.x;
  if (n < NNODE) dinv[n] = rsqrtf((float)cnt[n] + 1.0f);
}
__global__ void fill_bucket(const int* __restrict__ row, const int* __restrict__ col,
                            int* __restrict__ cur, int* __restrict__ bucket){
  int e = blockIdx.x*256 + threadIdx.x;
  if (e >= EEDG) return;
  int c = col[e];
  int s = atomicAdd(&cur[c], 1);
  if (s < CAP) bucket[c*CAP + s] = row[e];
}

// ---------------- fused: aggregate + bg + GELU + residual + LN + head logits ----------------
// one wave per node; lane owns 4 channels (c0 = lane*4). All fp32 except xl/x (bf16 hi/lo).
__global__ __launch_bounds__(256) void fused_agg(
    const u16* __restrict__ xl, const u16* __restrict__ xhi, const u16* __restrict__ xlo,
    const int* __restrict__ cnt, const float* __restrict__ dinv, const int* __restrict__ bucket,
    const float* __restrict__ bgv, const float* __restrict__ gam, const float* __restrict__ bet,
    const float* __restrict__ qv, float* __restrict__ outg, float* __restrict__ logits)
{
  int wid = threadIdx.x>>6, lane = threadIdx.x&63;
  int n = blockIdx.x*4 + wid;
  int c0 = lane*4;
  float dn = dinv[n];

  ushort4 v = *reinterpret_cast<const ushort4*>(xl + (size_t)n*256 + c0);
  float wself = dn*dn;
  float a0 = bf2f(v.x)*wself, a1 = bf2f(v.y)*wself, a2 = bf2f(v.z)*wself, a3 = bf2f(v.w)*wself;

  int lim = cnt[n]; if (lim > CAP) lim = CAP;
  for (int s=0; s<lim; ++s) {
    int r = bucket[n*CAP + s];
    float w = dinv[r]*dn;
    ushort4 u = *reinterpret_cast<const ushort4*>(xl + (size_t)r*256 + c0);
    a0 += bf2f(u.x)*w; a1 += bf2f(u.y)*w; a2 += bf2f(u.z)*w; a3 += bf2f(u.w)*w;
  }

  ushort4 xh = *reinterpret_cast<const ushort4*>(xhi + (size_t)n*256 + c0);
  float x0 = bf2f(xh.x), x1 = bf2f(xh.y), x2 = bf2f(xh.z), x3 = bf2f(xh.w);
  if (xlo) {
    ushort4 xw = *reinterpret_cast<const ushort4*>(xlo + (size_t)n*256 + c0);
    x0 += bf2f(xw.x); x1 += bf2f(xw.y); x2 += bf2f(xw.z); x3 += bf2f(xw.w);
  }
  float4 bgb = *reinterpret_cast<const float4*>(bgv + c0);
  float g0 = gelu_exact(a0 + bgb.x) + x0;
  float g1 = gelu_exact(a1 + bgb.y) + x1;
  float g2 = gelu_exact(a2 + bgb.z) + x2;
  float g3 = gelu_exact(a3 + bgb.w) + x3;

  float s1 = g0+g1+g2+g3;
  float s2 = g0*g0+g1*g1+g2*g2+g3*g3;
  for (int off=32; off; off>>=1){ s1 += __shfl_xor(s1, off); s2 += __shfl_xor(s2, off); }
  float mu  = s1*(1.0f/256.0f);
  float var = s2*(1.0f/256.0f) - mu*mu;
  float inv = rsqrtf(var + 1e-5f);

  float4 gb = *reinterpret_cast<const float4*>(gam + c0);
  float4 bb = *reinterpret_cast<const float4*>(bet + c0);
  float y0 = (g0-mu)*inv*gb.x + bb.x;
  float y1 = (g1-mu)*inv*gb.y + bb.y;
  float y2 = (g2-mu)*inv*gb.z + bb.z;
  float y3 = (g3-mu)*inv*gb.w + bb.w;

  float4 o; o.x=y0; o.y=y1; o.z=y2; o.w=y3;
  *reinterpret_cast<float4*>(outg + (size_t)n*256 + c0) = o;

  float4 qb = *reinterpret_cast<const float4*>(qv + c0);
  float dq = y0*qb.x + y1*qb.y + y2*qb.z + y3*qb.w;
  dq += __shfl_xor(dq,1); dq += __shfl_xor(dq,2); dq += __shfl_xor(dq,4);
  if ((lane&7)==0){
    int b = n>>12, p = n&4095, h = lane>>3;
    logits[(size_t)(b*8+h)*4096 + p] = dq*10.0f;   // 1/TEMPERATURE
  }
}

// ---------------- row softmax over 4096 (fp32 in/out) ----------------
__global__ __launch_bounds__(256) void softmax_rows(const float* __restrict__ logits, float* __restrict__ outa){
  int r = blockIdx.x;
  const float* p = logits + (size_t)r*4096;
  int tid = threadIdx.x;
  int wid = tid>>6, lane = tid&63;
  __shared__ float redm[4];
  __shared__ float reds[4];
  float v[16];
  float mx = -1e30f;
  for (int i=0;i<16;++i){ v[i] = p[tid + i*256]; mx = fmaxf(mx, v[i]); }
  for (int off=32; off; off>>=1) mx = fmaxf(mx, __shfl_xor(mx, off));
  if (lane==0) redm[wid]=mx;
  __syncthreads();
  mx = fmaxf(fmaxf(redm[0],redm[1]), fmaxf(redm[2],redm[3]));
  float sum = 0.f;
  for (int i=0;i<16;++i){ v[i] = expf(v[i]-mx); sum += v[i]; }
  for (int off=32; off; off>>=1) sum += __shfl_xor(sum, off);
  if (lane==0) reds[wid]=sum;
  __syncthreads();
  sum = reds[0]+reds[1]+reds[2]+reds[3];
  float rinv = 1.0f/sum;
  for (int i=0;i<16;++i) outa[(size_t)r*4096 + tid + i*256] = v[i]*rinv;
}

extern "C" void kernel_launch(void* const* d_in, const int* in_sizes, int n_in,
                              void* d_out, int out_size, void* d_ws, size_t ws_size,
                              hipStream_t stream)
{
  const float* img  = (const float*)d_in[0];
  const int* edges  = (const int*)d_in[1];   // [2][E] int32: row=edges, col=edges+E
  const float* Wp   = (const float*)d_in[2];
  const float* bp   = (const float*)d_in[3];
  const float* Wg   = (const float*)d_in[4];
  const float* bg   = (const float*)d_in[5];
  const float* lng  = (const float*)d_in[6];
  const float* lnb  = (const float*)d_in[7];
  const float* dq   = (const float*)d_in[8];
  char* ws = (char*)d_ws;

  constexpr size_t REG      = (size_t)NNODE*CC*2;                 // 67,108,864 (one bf16 node array)
  constexpr size_t GRAPHBLK = 524288u*3 + (size_t)NNODE*CAP*4 + (size_t)256*4096*4; // 22,544,384
  constexpr size_t WTS      = 4u*131072;                          // WpT/WgT hi+lo
  const bool full = (ws_size >= 4*REG + WTS);
  if (!full && ws_size < 2*REG + GRAPHBLK + WTS) return;          // cannot run

  u16 *AT_hi, *AT_lo, *x_hi, *x_lo, *xl;
  char* gblk; char* wts;
  if (full) {
    AT_hi = (u16*)(ws + 0);        AT_lo = (u16*)(ws + REG);
    x_hi  = (u16*)(ws + 2*REG);    x_lo  = (u16*)(ws + 3*REG);
    wts   = ws + 4*REG;
    xl    = AT_hi;                 // overlay: AT dead after GEMM1
    gblk  = (char*)AT_lo;          // overlay: graph prep runs after GEMM1
  } else {
    AT_hi = (u16*)(ws + 0);        AT_lo = nullptr;
    x_hi  = (u16*)(ws + REG);      x_lo  = nullptr;
    gblk  = ws + 2*REG;
    wts   = ws + 2*REG + GRAPHBLK;
    xl    = AT_hi;
  }
  u16* WpT_hi = (u16*)(wts);
  u16* WpT_lo = (u16*)(wts + 131072);
  u16* WgT_hi = (u16*)(wts + 262144);
  u16* WgT_lo = (u16*)(wts + 393216);
  int*   cnt    = (int*)(gblk);
  int*   cur    = (int*)(gblk + 524288);
  float* dinv   = (float*)(gblk + 1048576);
  int*   bucket = (int*)(gblk + 1572864);
  float* logits = (float*)(gblk + 1572864 + (size_t)NNODE*CAP*4);

  // weight transpose+split (tiny), img transpose+split
  transpose_split<<<dim3(4,4,1),   256, 0, stream>>>(Wp, WpT_hi, WpT_lo, 256, 256, 0, 0);
  transpose_split<<<dim3(4,4,1),   256, 0, stream>>>(Wg, WgT_hi, WgT_lo, 256, 256, 0, 0);
  transpose_split<<<dim3(64,4,32), 256, 0, stream>>>(img, AT_hi, AT_lo, 256, 4096,
                                                     (size_t)CC*HWSZ, (size_t)HWSZ*CC);

  // x = imgT @ Wp + bp   (bf16 hi/lo out, ~fp32 accurate)
  gemm_split<<<dim3(1024,2), 256, 0, stream>>>(AT_hi, AT_lo, WpT_hi, WpT_lo, bp, x_hi, x_lo);

  // graph prep (overlays AT_lo region in full mode -> must be after GEMM1)
  hipMemsetAsync(cnt, 0, 524288, stream);
  hipMemsetAsync(cur, 0, 524288, stream);
  count_deg  <<<2048, 256, 0, stream>>>(edges+EEDG, cnt);
  calc_dinv  <<<512,  256, 0, stream>>>(cnt, dinv);
  fill_bucket<<<2048, 256, 0, stream>>>(edges, edges+EEDG, cur, bucket);

  // xl = x @ Wg  (bf16 hi out only)
  gemm_split<<<dim3(1024,2), 256, 0, stream>>>(x_hi, x_lo, WgT_hi, WgT_lo, nullptr, xl, nullptr);

  float* outg = (float*)d_out;
  float* outa = (float*)d_out + (size_t)NNODE*CC;
  fused_agg<<<NNODE/4, 256, 0, stream>>>(xl, x_hi, x_lo, cnt, dinv, bucket,
                                         bg, lng, lnb, dq, outg, logits);
  softmax_rows<<<256, 256, 0, stream>>>(logits, outa);
}

// Round 3
// 359.438 us; speedup vs baseline: 1.2172x; 1.2172x over previous
//
#include <hip/hip_runtime.h>

typedef unsigned short u16;
typedef __attribute__((ext_vector_type(8))) short short8;
typedef __attribute__((ext_vector_type(4))) float f32x4;

#define AS1C(p) ((const __attribute__((address_space(1))) void*)(p))
#define AS3(p)  ((__attribute__((address_space(3))) void*)(p))

constexpr int CC    = 256;      // channels
constexpr int HWSZ  = 4096;     // H*W
constexpr int NNODE = 131072;   // B*H*W
constexpr int EEDG  = 524288;   // edges
constexpr int CAP   = 32;       // per-node bucket capacity (Poisson(4): P(deg>=32)~1e-18)

__device__ __forceinline__ float bf2f(u16 h){ unsigned u = ((unsigned)h)<<16; float f; __builtin_memcpy(&f,&u,4); return f; }
__device__ __forceinline__ u16 f2bf(float f){ unsigned u; __builtin_memcpy(&u,&f,4); return (u16)((u + 0x7FFFu + ((u>>16)&1u))>>16); }
__device__ __forceinline__ float gelu_exact(float v){ return 0.5f*v*(1.0f + erff(v*0.7071067811865476f)); }

// unpack 8 bf16 (as uint4) -> 8 floats; channel 2j = low half of word j
__device__ __forceinline__ void unpack8(uint4 q, float f[8]){
  unsigned w0=q.x,w1=q.y,w2=q.z,w3=q.w;
  unsigned l0=w0<<16, h0=w0&0xffff0000u, l1=w1<<16, h1=w1&0xffff0000u;
  unsigned l2=w2<<16, h2=w2&0xffff0000u, l3=w3<<16, h3=w3&0xffff0000u;
  __builtin_memcpy(&f[0],&l0,4); __builtin_memcpy(&f[1],&h0,4);
  __builtin_memcpy(&f[2],&l1,4); __builtin_memcpy(&f[3],&h1,4);
  __builtin_memcpy(&f[4],&l2,4); __builtin_memcpy(&f[5],&h2,4);
  __builtin_memcpy(&f[6],&l3,4); __builtin_memcpy(&f[7],&h3,4);
}

// ---------------- fp32 64x64 tiled transpose + bf16 hi/lo split ----------------
__global__ __launch_bounds__(256) void transpose_split(const float* __restrict__ src,
                                                       u16* __restrict__ dhi, u16* __restrict__ dlo,
                                                       int R, int Ccols, size_t sb_in, size_t sb_out)
{
  __shared__ float t[64][65];
  const float* s = src + blockIdx.z*sb_in + (size_t)(blockIdx.y*64)*Ccols + blockIdx.x*64;
  size_t obase   = blockIdx.z*sb_out + (size_t)(blockIdx.x*64)*R + blockIdx.y*64;
  int tid = threadIdx.x;
  for (int i=0;i<4;++i){
    int idx = i*256 + tid;
    int r = idx>>4, q = idx&15;
    float4 v = *(const float4*)(s + (size_t)r*Ccols + q*4);
    t[r][q*4+0]=v.x; t[r][q*4+1]=v.y; t[r][q*4+2]=v.z; t[r][q*4+3]=v.w;
  }
  __syncthreads();
  for (int i=0;i<2;++i){
    int idx = i*256 + tid;
    int rr = idx>>3, ch = idx&7;
    u16 hi[8], lo[8];
    for (int j=0;j<8;++j){
      float f = t[ch*8+j][rr];
      u16 h = f2bf(f); hi[j] = h;
      lo[j] = f2bf(f - bf2f(h));
    }
    *(uint4*)(dhi + obase + (size_t)rr*R + ch*8) = *(uint4*)hi;
    if (dlo) *(uint4*)(dlo + obase + (size_t)rr*R + ch*8) = *(uint4*)lo;
  }
}

// ---------------- split-precision GEMM (unchanged structure) ----------------
__global__ __launch_bounds__(256) void gemm_split(const u16* __restrict__ Ahi, const u16* __restrict__ Alo,
                                                  const u16* __restrict__ Bhi, const u16* __restrict__ Blo,
                                                  const float* __restrict__ bias,
                                                  u16* __restrict__ Chi, u16* __restrict__ Clo)
{
  __shared__ u16 As_hi[128*32];
  __shared__ u16 As_lo[128*32];
  __shared__ u16 Bs_hi[128*32];
  __shared__ u16 Bs_lo[128*32];
  const int tid  = threadIdx.x;
  const int wid  = tid>>6, lane = tid&63;
  const int row0 = blockIdx.x*128;
  const int col0 = blockIdx.y*128;
  const int gk = lane>>4, ml = lane&15;
  const int wm = wid>>1, wn = wid&1;
  const bool haslo = (Alo != nullptr);

  f32x4 acc[4][4];
  for (int i=0;i<4;++i) for (int j=0;j<4;++j) for (int e=0;e<4;++e) acc[i][j][e]=0.f;

  for (int kt=0; kt<256; kt+=32) {
#define STAGE(G, S, rbase)                                                            \
    for (int it=0; it<2; ++it) {                                                      \
      int qb = (it*4+wid)*64;                                                         \
      int qq = qb + lane;                                                             \
      int m  = qq>>2, sc = qq&3;                                                      \
      int gs = sc ^ ((m>>1)&3);                                                       \
      __builtin_amdgcn_global_load_lds(AS1C(G + (size_t)((rbase)+m)*256 + kt + gs*8), \
                                       AS3(S + (size_t)qb*8), 16, 0, 0);              \
    }
    STAGE(Ahi, As_hi, row0)
    if (haslo) { STAGE(Alo, As_lo, row0) }
    STAGE(Bhi, Bs_hi, col0)
    STAGE(Blo, Bs_lo, col0)
#undef STAGE
    asm volatile("s_waitcnt vmcnt(0)" ::: "memory");
    __syncthreads();

    short8 ah[4], al[4], bh[4], bl[4];
    for (int f=0; f<4; ++f) {
      int m  = wm*64 + f*16 + ml;
      int sa = gk ^ ((m>>1)&3);
      ah[f] = *(const short8*)&As_hi[m*32 + sa*8];
      if (haslo) al[f] = *(const short8*)&As_lo[m*32 + sa*8];
      int j  = wn*64 + f*16 + ml;
      int sb = gk ^ ((j>>1)&3);
      bh[f] = *(const short8*)&Bs_hi[j*32 + sb*8];
      bl[f] = *(const short8*)&Bs_lo[j*32 + sb*8];
    }
    for (int fm=0; fm<4; ++fm)
      for (int fn=0; fn<4; ++fn) {
        acc[fm][fn] = __builtin_amdgcn_mfma_f32_16x16x32_bf16(ah[fm], bh[fn], acc[fm][fn], 0, 0, 0);
        if (haslo)
          acc[fm][fn] = __builtin_amdgcn_mfma_f32_16x16x32_bf16(al[fm], bh[fn], acc[fm][fn], 0, 0, 0);
        acc[fm][fn] = __builtin_amdgcn_mfma_f32_16x16x32_bf16(ah[fm], bl[fn], acc[fm][fn], 0, 0, 0);
      }
    __syncthreads();
  }

  float bv[4];
  for (int f=0; f<4; ++f) bv[f] = bias ? bias[col0 + wn*64 + f*16 + ml] : 0.f;
  for (int fm=0; fm<4; ++fm) {
    int rbase = row0 + wm*64 + fm*16 + gk*4;
    for (int fn=0; fn<4; ++fn) {
      int ccol = col0 + wn*64 + fn*16 + ml;
      for (int i=0;i<4;++i) {
        float f = acc[fm][fn][i] + bv[fn];
        size_t idx = (size_t)(rbase+i)*256 + ccol;
        u16 h = f2bf(f);
        Chi[idx] = h;
        if (Clo) Clo[idx] = f2bf(f - bf2f(h));
      }
    }
  }
}

// ---------------- graph prep: single edge pass ----------------
__global__ void fill_all(const int* __restrict__ row, const int* __restrict__ col,
                         int* __restrict__ cur, int* __restrict__ bucket){
  int e = blockIdx.x*256 + threadIdx.x;
  if (e >= EEDG) return;
  int c = col[e];
  int s = atomicAdd(&cur[c], 1);
  if (s < CAP) bucket[(size_t)c*CAP + s] = row[e];
}
__global__ void calc_dinv(const int* __restrict__ cnt, float* __restrict__ dinv){
  int n = blockIdx.x*256 + threadIdx.x;
  if (n < NNODE) dinv[n] = rsqrtf((float)cnt[n] + 1.0f);
}

// ---------------- fused: aggregate + bg + GELU + residual + LN + head logits ----------------
// 2 nodes per wave (half-wave each), 8 channels/lane. Bucket+weights preloaded via
// lanes and broadcast with shfl; gather loop unrolled 2 -> 4 independent 16B loads
// in flight per wave (latency fix for the serial dependent chain).
__global__ __launch_bounds__(256) void fused_agg(
    const u16* __restrict__ xl, const u16* __restrict__ xhi, const u16* __restrict__ xlo,
    const int* __restrict__ cnt, const float* __restrict__ dinv, const int* __restrict__ bucket,
    const float* __restrict__ bgv, const float* __restrict__ gam, const float* __restrict__ bet,
    const float* __restrict__ qv, float* __restrict__ outg, float* __restrict__ logits)
{
  const int wid = threadIdx.x>>6, lane = threadIdx.x&63;
  const int half = lane>>5, sl = lane&31;
  const int n = blockIdx.x*8 + wid*2 + half;
  const int c0 = sl*8;
  const float dn = dinv[n];
  int lim = cnt[n]; if (lim > CAP) lim = CAP;

  // lane-parallel preload of bucket row + neighbor weights (sanitize poison slots)
  int rl = bucket[(size_t)n*CAP + sl];
  if (sl >= lim) rl = n;                 // never form addresses from garbage
  float wl = (sl < lim) ? dinv[rl]*dn : 0.0f;

  float a[8];
  {
    uint4 q = *(const uint4*)(xl + (size_t)n*256 + c0);
    unpack8(q, a);
    float wself = dn*dn;
    #pragma unroll
    for (int j=0;j<8;++j) a[j] *= wself;
  }

  for (int s=0; s<lim; s+=2) {
    int  src0 = half*32 + s;
    int  r0   = __shfl(rl, src0);
    float w0  = __shfl(wl, src0);
    bool p1   = (s+1 < lim);
    int  src1 = half*32 + (p1 ? s+1 : s);
    int  r1   = __shfl(rl, src1);
    float w1  = p1 ? __shfl(wl, src1) : 0.0f;
    uint4 q0 = *(const uint4*)(xl + (size_t)r0*256 + c0);
    uint4 q1 = *(const uint4*)(xl + (size_t)r1*256 + c0);
    float f0[8], f1[8];
    unpack8(q0, f0); unpack8(q1, f1);
    #pragma unroll
    for (int j=0;j<8;++j) a[j] += f0[j]*w0 + f1[j]*w1;
  }

  // residual x (hi + optional lo)
  float xv[8];
  {
    uint4 qh = *(const uint4*)(xhi + (size_t)n*256 + c0);
    unpack8(qh, xv);
    if (xlo) {
      uint4 ql = *(const uint4*)(xlo + (size_t)n*256 + c0);
      float xw[8]; unpack8(ql, xw);
      #pragma unroll
      for (int j=0;j<8;++j) xv[j] += xw[j];
    }
  }

  float4 b0 = *(const float4*)(bgv + c0), b1 = *(const float4*)(bgv + c0 + 4);
  float bgs[8] = {b0.x,b0.y,b0.z,b0.w,b1.x,b1.y,b1.z,b1.w};
  float g[8];
  float s1 = 0.f, s2 = 0.f;
  #pragma unroll
  for (int j=0;j<8;++j){
    g[j] = gelu_exact(a[j] + bgs[j]) + xv[j];
    s1 += g[j]; s2 += g[j]*g[j];
  }
  #pragma unroll
  for (int off=16; off; off>>=1){ s1 += __shfl_xor(s1, off); s2 += __shfl_xor(s2, off); }
  float mu  = s1*(1.0f/256.0f);
  float var = s2*(1.0f/256.0f) - mu*mu;
  float inv = rsqrtf(var + 1e-5f);

  float4 g0 = *(const float4*)(gam + c0), g1 = *(const float4*)(gam + c0 + 4);
  float4 e0 = *(const float4*)(bet + c0), e1 = *(const float4*)(bet + c0 + 4);
  float gms[8] = {g0.x,g0.y,g0.z,g0.w,g1.x,g1.y,g1.z,g1.w};
  float bts[8] = {e0.x,e0.y,e0.z,e0.w,e1.x,e1.y,e1.z,e1.w};
  float y[8];
  #pragma unroll
  for (int j=0;j<8;++j) y[j] = (g[j]-mu)*inv*gms[j] + bts[j];

  float4 o0 = {y[0],y[1],y[2],y[3]}, o1 = {y[4],y[5],y[6],y[7]};
  *reinterpret_cast<float4*>(outg + (size_t)n*256 + c0)     = o0;
  *reinterpret_cast<float4*>(outg + (size_t)n*256 + c0 + 4) = o1;

  float4 q0 = *(const float4*)(qv + c0), q1 = *(const float4*)(qv + c0 + 4);
  float qs[8] = {q0.x,q0.y,q0.z,q0.w,q1.x,q1.y,q1.z,q1.w};
  float dq = 0.f;
  #pragma unroll
  for (int j=0;j<8;++j) dq += y[j]*qs[j];
  dq += __shfl_xor(dq,1); dq += __shfl_xor(dq,2);
  if ((sl&3)==0){
    int b = n>>12, p = n&4095, h = sl>>2;
    logits[(size_t)(b*8+h)*4096 + p] = dq*10.0f;   // 1/TEMPERATURE
  }
}

// ---------------- row softmax over 4096 (fp32 in/out) ----------------
__global__ __launch_bounds__(256) void softmax_rows(const float* __restrict__ logits, float* __restrict__ outa){
  int r = blockIdx.x;
  const float* p = logits + (size_t)r*4096;
  int tid = threadIdx.x;
  int wid = tid>>6, lane = tid&63;
  __shared__ float redm[4];
  __shared__ float reds[4];
  float v[16];
  float mx = -1e30f;
  for (int i=0;i<16;++i){ v[i] = p[tid + i*256]; mx = fmaxf(mx, v[i]); }
  for (int off=32; off; off>>=1) mx = fmaxf(mx, __shfl_xor(mx, off));
  if (lane==0) redm[wid]=mx;
  __syncthreads();
  mx = fmaxf(fmaxf(redm[0],redm[1]), fmaxf(redm[2],redm[3]));
  float sum = 0.f;
  for (int i=0;i<16;++i){ v[i] = expf(v[i]-mx); sum += v[i]; }
  for (int off=32; off; off>>=1) sum += __shfl_xor(sum, off);
  if (lane==0) reds[wid]=sum;
  __syncthreads();
  sum = reds[0]+reds[1]+reds[2]+reds[3];
  float rinv = 1.0f/sum;
  for (int i=0;i<16;++i) outa[(size_t)r*4096 + tid + i*256] = v[i]*rinv;
}

extern "C" void kernel_launch(void* const* d_in, const int* in_sizes, int n_in,
                              void* d_out, int out_size, void* d_ws, size_t ws_size,
                              hipStream_t stream)
{
  const float* img  = (const float*)d_in[0];
  const int* edges  = (const int*)d_in[1];   // [2][E] int32: row=edges, col=edges+E
  const float* Wp   = (const float*)d_in[2];
  const float* bp   = (const float*)d_in[3];
  const float* Wg   = (const float*)d_in[4];
  const float* bg   = (const float*)d_in[5];
  const float* lng  = (const float*)d_in[6];
  const float* lnb  = (const float*)d_in[7];
  const float* dq   = (const float*)d_in[8];
  char* ws = (char*)d_ws;

  constexpr size_t REG      = (size_t)NNODE*CC*2;                 // 67,108,864
  constexpr size_t GRAPHBLK = 524288u*2 + (size_t)NNODE*CAP*4 + (size_t)256*4096*4; // ~21.8 MB
  constexpr size_t WTS      = 4u*131072;
  const bool full = (ws_size >= 4*REG + WTS);
  if (!full && ws_size < 2*REG + GRAPHBLK + WTS) return;

  u16 *AT_hi, *AT_lo, *x_hi, *x_lo, *xl;
  char* gblk; char* wts;
  if (full) {
    AT_hi = (u16*)(ws + 0);        AT_lo = (u16*)(ws + REG);
    x_hi  = (u16*)(ws + 2*REG);    x_lo  = (u16*)(ws + 3*REG);
    wts   = ws + 4*REG;
    xl    = AT_hi;                 // overlay: AT dead after GEMM1
    gblk  = (char*)AT_lo;          // overlay: graph prep runs after GEMM1
  } else {
    AT_hi = (u16*)(ws + 0);        AT_lo = nullptr;
    x_hi  = (u16*)(ws + REG);      x_lo  = nullptr;
    gblk  = ws + 2*REG;
    wts   = ws + 2*REG + GRAPHBLK;
    xl    = AT_hi;
  }
  u16* WpT_hi = (u16*)(wts);
  u16* WpT_lo = (u16*)(wts + 131072);
  u16* WgT_hi = (u16*)(wts + 262144);
  u16* WgT_lo = (u16*)(wts + 393216);
  int*   cur    = (int*)(gblk);
  float* dinv   = (float*)(gblk + 524288);
  int*   bucket = (int*)(gblk + 1048576);
  float* logits = (float*)(gblk + 1048576 + (size_t)NNODE*CAP*4);

  transpose_split<<<dim3(4,4,1),   256, 0, stream>>>(Wp, WpT_hi, WpT_lo, 256, 256, 0, 0);
  transpose_split<<<dim3(4,4,1),   256, 0, stream>>>(Wg, WgT_hi, WgT_lo, 256, 256, 0, 0);
  transpose_split<<<dim3(64,4,32), 256, 0, stream>>>(img, AT_hi, AT_lo, 256, 4096,
                                                     (size_t)CC*HWSZ, (size_t)HWSZ*CC);

  // x = imgT @ Wp + bp
  gemm_split<<<dim3(1024,2), 256, 0, stream>>>(AT_hi, AT_lo, WpT_hi, WpT_lo, bp, x_hi, x_lo);

  // graph prep (overlays AT_lo region -> must run after GEMM1)
  hipMemsetAsync(cur, 0, 524288, stream);
  fill_all <<<2048, 256, 0, stream>>>(edges, edges+EEDG, cur, bucket);
  calc_dinv<<<512,  256, 0, stream>>>(cur, dinv);

  // xl = x @ Wg
  gemm_split<<<dim3(1024,2), 256, 0, stream>>>(x_hi, x_lo, WgT_hi, WgT_lo, nullptr, xl, nullptr);

  float* outg = (float*)d_out;
  float* outa = (float*)d_out + (size_t)NNODE*CC;
  fused_agg<<<NNODE/8, 256, 0, stream>>>(xl, x_hi, x_lo, cur, dinv, bucket,
                                         bg, lng, lnb, dq, outg, logits);
  softmax_rows<<<256, 256, 0, stream>>>(logits, outa);
}